// Round 10
// baseline (1244.907 us; speedup 1.0000x reference)
//
#include <hip/hip_runtime.h>
#include <math.h>

#define BB 16
#define SS 512
#define HH 768
#define WW 256
#define VV 32000
#define NROWS (BB*WW)          // 4096
#define NCHUNK 500             // 64-wide v chunks
#define BM 128
#define BN 128
#define BK 64                  // fp8: 64 bytes per row per k-tile
#define NKT (HH/BK)            // 12
#define NMT (NROWS/BM)         // 32
#define NVT (VV/BN)            // 250
#define NWG (NMT*NVT)          // 8000
#define WSCALE 64.0f
#define WISCALE (1.0f/64.0f)

typedef __attribute__((ext_vector_type(8))) int i32x8;
typedef __attribute__((ext_vector_type(16))) float f32x16;

#define GLOAD16(g, l) __builtin_amdgcn_global_load_lds( \
    (const __attribute__((address_space(1))) void*)(g), \
    (__attribute__((address_space(3))) void*)(l), 16, 0, 0)

// pack 4 floats -> 4 fp8 e4m3 bytes (OCP)
__device__ __forceinline__ unsigned int pk4_fp8(float a0, float a1, float a2, float a3) {
    int r = __builtin_amdgcn_cvt_pk_fp8_f32(a0, a1, 0, false);
    r = __builtin_amdgcn_cvt_pk_fp8_f32(a2, a3, r, true);
    return (unsigned int)r;
}

// ---------------- pooling: one block per (b, w), fp8 output ----------------
// Stored layout: within each 16B slot, the two 8B halves are swapped when
// row bit3 is set (feeds the conflict-free LDS read swizzle).
__global__ __launch_bounds__(256) void pool_kernel(
    const float* __restrict__ h, const int* __restrict__ wid,
    unsigned int* __restrict__ pooled32)   // 4096 x 192 u32 (=768 fp8)
{
    int blk = blockIdx.x;
    int b = blk >> 8;
    int w = blk & 255;
    int tid = threadIdx.x;
    __shared__ int s_wid[SS];
    for (int i = tid; i < SS; i += 256) s_wid[i] = wid[b*SS + i];
    __syncthreads();
    int lo = 0, hi = SS;
    while (lo < hi) { int mid = (lo + hi) >> 1; if (s_wid[mid] < w) lo = mid + 1; else hi = mid; }
    int start = lo;
    hi = SS;
    while (lo < hi) { int mid = (lo + hi) >> 1; if (s_wid[mid] <= w) lo = mid + 1; else hi = mid; }
    int end = lo;
    int cnt = end - start;

    if (tid < 192) {
        float4 a = {0.f, 0.f, 0.f, 0.f};
        const float* hb = h + (size_t)b*SS*HH;
        for (int s = start; s < end; ++s) {
            float4 r = *(const float4*)&hb[(size_t)s*HH + tid*4];
            a.x += r.x; a.y += r.y; a.z += r.z; a.w += r.w;
        }
        float inv = (cnt > 0) ? (1.0f / (float)cnt) : 0.0f;
        int p = (blk >> 3) & 1;                 // row bit3 -> swap 8B halves
        pooled32[blk*192 + (tid ^ (p << 1))] = pk4_fp8(a.x*inv, a.y*inv, a.z*inv, a.w*inv);
    }
}

// ------- convert + transpose W: (768,32000) f32 -> (32000,768) fp8 (x64 scale) -------
// Same half-swap-by-row-bit3 storage as pooled.
__global__ __launch_bounds__(256) void wt_kernel(
    const float* __restrict__ Wc, unsigned char* __restrict__ Wt)
{
    const int v0 = blockIdx.x * 64;
    const int k0 = blockIdx.y * 64;
    const int t = threadIdx.x;
    __shared__ float S[64][65];
    #pragma unroll
    for (int j = 0; j < 4; ++j) {
        int idx = t + j*256;
        int kr = idx >> 4;
        int vs = idx & 15;
        float4 f = *(const float4*)&Wc[(size_t)(k0+kr)*VV + v0 + vs*4];
        S[kr][vs*4+0] = f.x; S[kr][vs*4+1] = f.y;
        S[kr][vs*4+2] = f.z; S[kr][vs*4+3] = f.w;
    }
    __syncthreads();
    #pragma unroll
    for (int j = 0; j < 2; ++j) {
        int idx = t + j*256;
        int vi = idx >> 3;     // 0..63 (row within tile)
        int ks = idx & 7;      // 0..7 (8B seg)
        float f[8];
        #pragma unroll
        for (int i = 0; i < 8; ++i) f[i] = S[ks*8+i][vi] * WSCALE;
        uint2 o;
        o.x = pk4_fp8(f[0], f[1], f[2], f[3]);
        o.y = pk4_fp8(f[4], f[5], f[6], f[7]);
        int p = (vi >> 3) & 1;                  // row bit3 -> swap 8B halves
        *(uint2*)&Wt[(size_t)(v0+vi)*HH + k0 + (ks ^ p)*8] = o;
    }
}

// ------- MX-fp8 MFMA GEMM (32x32x64 f8f6f4, unit scales), 128x128 tile -------
// 256 threads = 4 waves (2M x 2N), wave tile 64x64 = 2x2 frags of 32x32,
// acc = 2x2 f32x16 = 64 regs. LDS 2 dbuf x (8KB A + 8KB B) = 32 KB ->
// 4 blocks/CU (launch_bounds(256,4) caps regs at 128).
// Fragment layout: A row = lane&31, k = (lane>>5)*32 + e (8 VGPRs = 32 fp8);
// B symmetric. Reads = 4x b64 per fragment through the same zero-conflict
// XOR layout as R9 (fixed idx8, 16 consecutive rows per 16-lane phase).
// C/D: col = lane&31, row = (reg&3) + 8*(reg>>2) + 4*(lane>>5).
__global__ __launch_bounds__(256, 4) void logits_kernel(
    const unsigned char* __restrict__ Pb, const unsigned char* __restrict__ Wt,
    const float* __restrict__ bc, const int* __restrict__ targets,
    float* __restrict__ pmax, float* __restrict__ psum,
    float* __restrict__ tlogit)
{
    __shared__ unsigned char Alds[2][BM*BK];   // 2 x 8 KB
    __shared__ unsigned char Blds[2][BN*BK];   // 2 x 8 KB

    // XCD swizzle (NWG = 8000, divisible by 8), m-minor within XCD chunk
    const int id = blockIdx.x;
    const int wg = (id & 7) * (NWG/8) + (id >> 3);
    const int mt = wg % NMT;
    const int vt = wg / NMT;

    const int t = threadIdx.x;
    const int w = t >> 6;           // wave 0..3
    const int lane = t & 63;
    const int c31 = lane & 31;
    const int kg = lane >> 5;       // k-group 0..1
    const int wr = w >> 1;          // 0..1 (M)
    const int wc = w & 1;           // 0..1 (N)
    const int row0 = mt * BM;
    const int v0 = vt * BN;

    // staging: one call = 64 lanes x 16 B = 16 rows x 64 B; lane = rr*4 + s
    const int rr = lane >> 2;                     // 0..15 row within call
    const int sg = (lane & 3) ^ ((rr >> 1) & 3);  // pre-swizzled global 16B slot

    #define STAGE(BUF, KT) do {                                                   \
        const int k0_ = (KT) * BK;                                                \
        _Pragma("unroll")                                                         \
        for (int j_ = 0; j_ < 2; ++j_) {                                          \
            int ca_ = w*2 + j_;                                                   \
            GLOAD16(Pb + (size_t)(row0 + ca_*16 + rr)*HH + k0_ + sg*16,           \
                    &Alds[BUF][ca_*1024]);                                        \
            GLOAD16(Wt + (size_t)(v0 + ca_*16 + rr)*HH + k0_ + sg*16,             \
                    &Blds[BUF][ca_*1024]);                                        \
        }                                                                         \
    } while (0)

    f32x16 acc[2][2];
    #pragma unroll
    for (int mf = 0; mf < 2; ++mf)
        #pragma unroll
        for (int nf = 0; nf < 2; ++nf)
            #pragma unroll
            for (int e = 0; e < 16; ++e)
                acc[mf][nf][e] = 0.f;

    STAGE(0, 0);
    __syncthreads();

    for (int kt = 0; kt < NKT; ++kt) {
        const int buf = kt & 1;
        if (kt + 1 < NKT) STAGE(buf ^ 1, kt + 1);

        i32x8 af[2], bfv[2];
        #pragma unroll
        for (int mf = 0; mf < 2; ++mf) {
            const int row = wr*64 + mf*32 + c31;
            union { long q[4]; i32x8 v; } u;
            #pragma unroll
            for (int j = 0; j < 4; ++j) {
                const int idx8 = kg*4 + j;
                const int off = (((idx8 >> 1) ^ ((row >> 1) & 3)) << 4)
                              | (((idx8 & 1) ^ ((row >> 3) & 1)) << 3);
                u.q[j] = *(const long*)&Alds[buf][row*BK + off];
            }
            af[mf] = u.v;
        }
        #pragma unroll
        for (int nf = 0; nf < 2; ++nf) {
            const int col = wc*64 + nf*32 + c31;
            union { long q[4]; i32x8 v; } u;
            #pragma unroll
            for (int j = 0; j < 4; ++j) {
                const int idx8 = kg*4 + j;
                const int off = (((idx8 >> 1) ^ ((col >> 1) & 3)) << 4)
                              | (((idx8 & 1) ^ ((col >> 3) & 1)) << 3);
                u.q[j] = *(const long*)&Blds[buf][col*BK + off];
            }
            bfv[nf] = u.v;
        }

        #pragma unroll
        for (int mf = 0; mf < 2; ++mf)
            #pragma unroll
            for (int nf = 0; nf < 2; ++nf)
                acc[mf][nf] = __builtin_amdgcn_mfma_scale_f32_32x32x64_f8f6f4(
                    af[mf], bfv[nf], acc[mf][nf], 0, 0,
                    0, 0x7F7F7F7F, 0, 0x7F7F7F7F);   // fp8/fp8, scales = 2^0

        __syncthreads();
    }

    // epilogue: unscale + bias + per-row max/sumexp over this wave's 64 cols
    const int cchunk = vt*2 + wc;
    float bias0 = bc[v0 + wc*64 + c31];
    float bias1 = bc[v0 + wc*64 + 32 + c31];

    #pragma unroll
    for (int mf = 0; mf < 2; ++mf) {
        #pragma unroll
        for (int r = 0; r < 16; ++r) {
            const int row = row0 + wr*64 + mf*32 + (r & 3) + 8*(r >> 2) + 4*kg;
            float va = acc[mf][0][r]*WISCALE + bias0;
            float vb = acc[mf][1][r]*WISCALE + bias1;
            float mx = fmaxf(va, vb);
            #pragma unroll
            for (int off = 1; off < 32; off <<= 1)
                mx = fmaxf(mx, __shfl_xor(mx, off, 32));
            float se = __expf(va - mx) + __expf(vb - mx);
            #pragma unroll
            for (int off = 1; off < 32; off <<= 1)
                se += __shfl_xor(se, off, 32);
            if (c31 == 0) {
                pmax[(size_t)row*NCHUNK + cchunk] = mx;
                psum[(size_t)row*NCHUNK + cchunk] = se;
            }
            int tg = targets[row];
            if (tg == v0 + wc*64 + c31)           tlogit[row] = va;
            else if (tg == v0 + wc*64 + 32 + c31) tlogit[row] = vb;
        }
    }
}

// ---------------- combine chunk partials -> per-row loss ----------------
__global__ __launch_bounds__(256) void reduce_kernel(
    const float* __restrict__ pmax, const float* __restrict__ psum,
    const float* __restrict__ tlogit, const int* __restrict__ targets,
    float* __restrict__ rowloss)
{
    const int row = blockIdx.x;
    const int tid = threadIdx.x;
    float m0 = (tid       < NCHUNK) ? pmax[(size_t)row*NCHUNK + tid]       : -INFINITY;
    float m1 = (tid + 256 < NCHUNK) ? pmax[(size_t)row*NCHUNK + tid + 256] : -INFINITY;
    float mw = fmaxf(m0, m1);
    #pragma unroll
    for (int off = 1; off < 64; off <<= 1)
        mw = fmaxf(mw, __shfl_xor(mw, off));
    __shared__ float smax[4];
    __shared__ float ssum[4];
    const int wave = tid >> 6;
    if ((tid & 63) == 0) smax[wave] = mw;
    __syncthreads();
    float mx = fmaxf(fmaxf(smax[0], smax[1]), fmaxf(smax[2], smax[3]));
    float s = 0.f;
    if (tid       < NCHUNK) s += psum[(size_t)row*NCHUNK + tid]       * __expf(m0 - mx);
    if (tid + 256 < NCHUNK) s += psum[(size_t)row*NCHUNK + tid + 256] * __expf(m1 - mx);
    #pragma unroll
    for (int off = 1; off < 64; off <<= 1)
        s += __shfl_xor(s, off);
    if ((tid & 63) == 0) ssum[wave] = s;
    __syncthreads();
    if (tid == 0) {
        float st = ssum[0] + ssum[1] + ssum[2] + ssum[3];
        float lse = mx + logf(st);
        int tg = targets[row];
        rowloss[row] = (tg != 0) ? (lse - tlogit[row]) : 0.0f;
    }
}

// ---------------- final sum over rows ----------------
__global__ __launch_bounds__(256) void finalize_kernel(
    const float* __restrict__ rowloss, const int* __restrict__ targets,
    float* __restrict__ out)
{
    const int tid = threadIdx.x;
    float s = 0.f; float c = 0.f;
    for (int i = tid; i < NROWS; i += 256) {
        s += rowloss[i];
        c += (targets[i] != 0) ? 1.0f : 0.0f;
    }
    #pragma unroll
    for (int off = 1; off < 64; off <<= 1) {
        s += __shfl_xor(s, off);
        c += __shfl_xor(c, off);
    }
    __shared__ float ss[4], sc[4];
    const int wave = tid >> 6;
    if ((tid & 63) == 0) { ss[wave] = s; sc[wave] = c; }
    __syncthreads();
    if (tid == 0) {
        float st = ss[0]+ss[1]+ss[2]+ss[3];
        float ct = sc[0]+sc[1]+sc[2]+sc[3];
        out[0] = st / fmaxf(ct, 1.0f);
    }
}

extern "C" void kernel_launch(void* const* d_in, const int* in_sizes, int n_in,
                              void* d_out, int out_size, void* d_ws, size_t ws_size,
                              hipStream_t stream) {
    const float* h       = (const float*)d_in[0];   // (16,512,768) f32
    const int*   wid     = (const int*)  d_in[1];   // (16,512) i32
    const int*   targets = (const int*)  d_in[2];   // (16,256) i32
    const float* Wc      = (const float*)d_in[3];   // (768,32000) f32
    const float* bc      = (const float*)d_in[4];   // (32000,) f32
    float* out = (float*)d_out;

    unsigned char* pooled = (unsigned char*)d_ws;                // 4096*768 fp8
    unsigned char* Wt     = pooled + (size_t)NROWS*HH;           // 32000*768 fp8
    float* pmax  = (float*)(Wt + (size_t)HH*VV);                 // 4096*500
    float* psum  = pmax + (size_t)NROWS*NCHUNK;                  // 4096*500
    float* tlog  = psum + (size_t)NROWS*NCHUNK;                  // 4096
    float* rowl  = tlog + NROWS;                                 // 4096

    pool_kernel<<<NROWS, 256, 0, stream>>>(h, wid, (unsigned int*)pooled);
    wt_kernel<<<dim3(VV/64, HH/64), 256, 0, stream>>>(Wc, Wt);
    logits_kernel<<<NWG, 256, 0, stream>>>(
        pooled, Wt, bc, targets, pmax, psum, tlog);
    reduce_kernel<<<NROWS, 256, 0, stream>>>(pmax, psum, tlog, targets, rowl);
    finalize_kernel<<<1, 256, 0, stream>>>(rowl, targets, out);
}

// Round 11
// 1028.881 us; speedup vs baseline: 1.2100x; 1.2100x over previous
//
#include <hip/hip_runtime.h>
#include <math.h>

#define BB 16
#define SS 512
#define HH 768
#define WW 256
#define VV 32000
#define NROWS (BB*WW)          // 4096
#define NCHUNK 500             // 64-wide v chunks
#define BM 128
#define BN 128
#define BK 64                  // fp8: 64 bytes per row per k-tile
#define NKT (HH/BK)            // 12
#define NMT (NROWS/BM)         // 32
#define NVT (VV/BN)            // 250
#define NWG (NMT*NVT)          // 8000
#define WSCALE 64.0f
#define WISCALE (1.0f/64.0f)

typedef __attribute__((ext_vector_type(8))) int i32x8;
typedef __attribute__((ext_vector_type(16))) float f32x16;

#define GLOAD16(g, l) __builtin_amdgcn_global_load_lds( \
    (const __attribute__((address_space(1))) void*)(g), \
    (__attribute__((address_space(3))) void*)(l), 16, 0, 0)

// pack 4 floats -> 4 fp8 e4m3 bytes (OCP)
__device__ __forceinline__ unsigned int pk4_fp8(float a0, float a1, float a2, float a3) {
    int r = __builtin_amdgcn_cvt_pk_fp8_f32(a0, a1, 0, false);
    r = __builtin_amdgcn_cvt_pk_fp8_f32(a2, a3, r, true);
    return (unsigned int)r;
}

// ---------------- pooling: one block per (b, w), fp8 output ----------------
// Stored layout: within each 16B slot, the two 8B halves are swapped when
// row bit3 is set (feeds the conflict-free LDS read swizzle).
__global__ __launch_bounds__(256) void pool_kernel(
    const float* __restrict__ h, const int* __restrict__ wid,
    unsigned int* __restrict__ pooled32)   // 4096 x 192 u32 (=768 fp8)
{
    int blk = blockIdx.x;
    int b = blk >> 8;
    int w = blk & 255;
    int tid = threadIdx.x;
    __shared__ int s_wid[SS];
    for (int i = tid; i < SS; i += 256) s_wid[i] = wid[b*SS + i];
    __syncthreads();
    int lo = 0, hi = SS;
    while (lo < hi) { int mid = (lo + hi) >> 1; if (s_wid[mid] < w) lo = mid + 1; else hi = mid; }
    int start = lo;
    hi = SS;
    while (lo < hi) { int mid = (lo + hi) >> 1; if (s_wid[mid] <= w) lo = mid + 1; else hi = mid; }
    int end = lo;
    int cnt = end - start;

    if (tid < 192) {
        float4 a = {0.f, 0.f, 0.f, 0.f};
        const float* hb = h + (size_t)b*SS*HH;
        for (int s = start; s < end; ++s) {
            float4 r = *(const float4*)&hb[(size_t)s*HH + tid*4];
            a.x += r.x; a.y += r.y; a.z += r.z; a.w += r.w;
        }
        float inv = (cnt > 0) ? (1.0f / (float)cnt) : 0.0f;
        int p = (blk >> 3) & 1;                 // row bit3 -> swap 8B halves
        pooled32[blk*192 + (tid ^ (p << 1))] = pk4_fp8(a.x*inv, a.y*inv, a.z*inv, a.w*inv);
    }
}

// ------- convert + transpose W: (768,32000) f32 -> (32000,768) fp8 (x64 scale) -------
// Same half-swap-by-row-bit3 storage as pooled.
__global__ __launch_bounds__(256) void wt_kernel(
    const float* __restrict__ Wc, unsigned char* __restrict__ Wt)
{
    const int v0 = blockIdx.x * 64;
    const int k0 = blockIdx.y * 64;
    const int t = threadIdx.x;
    __shared__ float S[64][65];
    #pragma unroll
    for (int j = 0; j < 4; ++j) {
        int idx = t + j*256;
        int kr = idx >> 4;
        int vs = idx & 15;
        float4 f = *(const float4*)&Wc[(size_t)(k0+kr)*VV + v0 + vs*4];
        S[kr][vs*4+0] = f.x; S[kr][vs*4+1] = f.y;
        S[kr][vs*4+2] = f.z; S[kr][vs*4+3] = f.w;
    }
    __syncthreads();
    #pragma unroll
    for (int j = 0; j < 2; ++j) {
        int idx = t + j*256;
        int vi = idx >> 3;     // 0..63 (row within tile)
        int ks = idx & 7;      // 0..7 (8B seg)
        float f[8];
        #pragma unroll
        for (int i = 0; i < 8; ++i) f[i] = S[ks*8+i][vi] * WSCALE;
        uint2 o;
        o.x = pk4_fp8(f[0], f[1], f[2], f[3]);
        o.y = pk4_fp8(f[4], f[5], f[6], f[7]);
        int p = (vi >> 3) & 1;                  // row bit3 -> swap 8B halves
        *(uint2*)&Wt[(size_t)(v0+vi)*HH + k0 + (ks ^ p)*8] = o;
    }
}

// ------- MX-fp8 MFMA GEMM (32x32x64 f8f6f4, unit scales), 128x128 tile -------
// 256 threads = 4 waves (2M x 2N), wave tile 64x64 = 2x2 frags of 32x32.
// Named f32x16 accumulators (register-only; rule #20), fragment assembly via
// int2 loads + brace-init (NO union -> no scratch; that was R10's 5x regress).
// LDS 2 dbuf x (8KB A + 8KB B) = 32 KB -> 4 blocks/CU (launch_bounds(256,4)).
// Zero-conflict XOR LDS layout as R9. C/D layout: col = lane&31,
// row = (reg&3) + 8*(reg>>2) + 4*(lane>>5).
__global__ __launch_bounds__(256, 4) void logits_kernel(
    const unsigned char* __restrict__ Pb, const unsigned char* __restrict__ Wt,
    const float* __restrict__ bc, const int* __restrict__ targets,
    float* __restrict__ pmax, float* __restrict__ psum,
    float* __restrict__ tlogit)
{
    __shared__ unsigned char Alds[2][BM*BK];   // 2 x 8 KB
    __shared__ unsigned char Blds[2][BN*BK];   // 2 x 8 KB

    // XCD swizzle (NWG = 8000, divisible by 8), m-minor within XCD chunk
    const int id = blockIdx.x;
    const int wg = (id & 7) * (NWG/8) + (id >> 3);
    const int mt = wg % NMT;
    const int vt = wg / NMT;

    const int t = threadIdx.x;
    const int w = t >> 6;           // wave 0..3
    const int lane = t & 63;
    const int c31 = lane & 31;
    const int kg = lane >> 5;       // k-group 0..1
    const int wr = w >> 1;          // 0..1 (M)
    const int wc = w & 1;           // 0..1 (N)
    const int row0 = mt * BM;
    const int v0 = vt * BN;

    // staging: one call = 64 lanes x 16 B = 16 rows x 64 B; lane = rr*4 + s
    const int rr = lane >> 2;                     // 0..15 row within call
    const int sg = (lane & 3) ^ ((rr >> 1) & 3);  // pre-swizzled global 16B slot

    #define STAGE(BUF, KT) do {                                                   \
        const int k0_ = (KT) * BK;                                                \
        _Pragma("unroll")                                                         \
        for (int j_ = 0; j_ < 2; ++j_) {                                          \
            int ca_ = w*2 + j_;                                                   \
            GLOAD16(Pb + (size_t)(row0 + ca_*16 + rr)*HH + k0_ + sg*16,           \
                    &Alds[BUF][ca_*1024]);                                        \
            GLOAD16(Wt + (size_t)(v0 + ca_*16 + rr)*HH + k0_ + sg*16,             \
                    &Blds[BUF][ca_*1024]);                                        \
        }                                                                         \
    } while (0)

    f32x16 acc00 = (f32x16)(0.f), acc01 = (f32x16)(0.f);
    f32x16 acc10 = (f32x16)(0.f), acc11 = (f32x16)(0.f);

    STAGE(0, 0);
    __syncthreads();

    // register-only fragment load: 4x ds_read_b64 through the XOR layout
    #define LD_FRAG(DST, BASE, ROW) do {                                          \
        const int r_ = (ROW);                                                     \
        const int ro_ = r_ * BK;                                                  \
        const int s2_ = (r_ >> 1) & 3, s3_ = (r_ >> 3) & 1;                       \
        int2 q0_ = *(const int2*)((BASE) + ro_ + ((((kg*4+0)>>1)^s2_)<<4) + ((((kg*4+0)&1)^s3_)<<3)); \
        int2 q1_ = *(const int2*)((BASE) + ro_ + ((((kg*4+1)>>1)^s2_)<<4) + ((((kg*4+1)&1)^s3_)<<3)); \
        int2 q2_ = *(const int2*)((BASE) + ro_ + ((((kg*4+2)>>1)^s2_)<<4) + ((((kg*4+2)&1)^s3_)<<3)); \
        int2 q3_ = *(const int2*)((BASE) + ro_ + ((((kg*4+3)>>1)^s2_)<<4) + ((((kg*4+3)&1)^s3_)<<3)); \
        DST = (i32x8){q0_.x, q0_.y, q1_.x, q1_.y, q2_.x, q2_.y, q3_.x, q3_.y};    \
    } while (0)

    for (int kt = 0; kt < NKT; ++kt) {
        const int buf = kt & 1;
        if (kt + 1 < NKT) STAGE(buf ^ 1, kt + 1);

        const unsigned char* Ab = &Alds[buf][0];
        const unsigned char* Bb = &Blds[buf][0];

        i32x8 a0, a1, b0, b1;
        LD_FRAG(a0, Ab, wr*64 + c31);
        LD_FRAG(a1, Ab, wr*64 + 32 + c31);
        LD_FRAG(b0, Bb, wc*64 + c31);
        acc00 = __builtin_amdgcn_mfma_scale_f32_32x32x64_f8f6f4(
            a0, b0, acc00, 0, 0, 0, 0x7F7F7F7F, 0, 0x7F7F7F7F);
        acc10 = __builtin_amdgcn_mfma_scale_f32_32x32x64_f8f6f4(
            a1, b0, acc10, 0, 0, 0, 0x7F7F7F7F, 0, 0x7F7F7F7F);
        LD_FRAG(b1, Bb, wc*64 + 32 + c31);
        acc01 = __builtin_amdgcn_mfma_scale_f32_32x32x64_f8f6f4(
            a0, b1, acc01, 0, 0, 0, 0x7F7F7F7F, 0, 0x7F7F7F7F);
        acc11 = __builtin_amdgcn_mfma_scale_f32_32x32x64_f8f6f4(
            a1, b1, acc11, 0, 0, 0, 0x7F7F7F7F, 0, 0x7F7F7F7F);

        __syncthreads();
    }

    // epilogue: unscale + bias + per-row max/sumexp over this wave's 64 cols
    const int cchunk = vt*2 + wc;
    float bias0 = bc[v0 + wc*64 + c31];
    float bias1 = bc[v0 + wc*64 + 32 + c31];

    #define EPILOG(ACCL, ACCR, MF) do {                                           \
        _Pragma("unroll")                                                         \
        for (int r = 0; r < 16; ++r) {                                            \
            const int row = row0 + wr*64 + (MF)*32 + (r & 3) + 8*(r >> 2) + 4*kg; \
            float va = (ACCL)[r]*WISCALE + bias0;                                 \
            float vb = (ACCR)[r]*WISCALE + bias1;                                 \
            float mx = fmaxf(va, vb);                                             \
            _Pragma("unroll")                                                     \
            for (int off = 1; off < 32; off <<= 1)                                \
                mx = fmaxf(mx, __shfl_xor(mx, off, 32));                          \
            float se = __expf(va - mx) + __expf(vb - mx);                         \
            _Pragma("unroll")                                                     \
            for (int off = 1; off < 32; off <<= 1)                                \
                se += __shfl_xor(se, off, 32);                                    \
            if (c31 == 0) {                                                       \
                pmax[(size_t)row*NCHUNK + cchunk] = mx;                           \
                psum[(size_t)row*NCHUNK + cchunk] = se;                           \
            }                                                                     \
            int tg = targets[row];                                                \
            if (tg == v0 + wc*64 + c31)           tlogit[row] = va;               \
            else if (tg == v0 + wc*64 + 32 + c31) tlogit[row] = vb;               \
        }                                                                         \
    } while (0)

    EPILOG(acc00, acc01, 0);
    EPILOG(acc10, acc11, 1);
}

// ---------------- combine chunk partials -> per-row loss ----------------
__global__ __launch_bounds__(256) void reduce_kernel(
    const float* __restrict__ pmax, const float* __restrict__ psum,
    const float* __restrict__ tlogit, const int* __restrict__ targets,
    float* __restrict__ rowloss)
{
    const int row = blockIdx.x;
    const int tid = threadIdx.x;
    float m0 = (tid       < NCHUNK) ? pmax[(size_t)row*NCHUNK + tid]       : -INFINITY;
    float m1 = (tid + 256 < NCHUNK) ? pmax[(size_t)row*NCHUNK + tid + 256] : -INFINITY;
    float mw = fmaxf(m0, m1);
    #pragma unroll
    for (int off = 1; off < 64; off <<= 1)
        mw = fmaxf(mw, __shfl_xor(mw, off));
    __shared__ float smax[4];
    __shared__ float ssum[4];
    const int wave = tid >> 6;
    if ((tid & 63) == 0) smax[wave] = mw;
    __syncthreads();
    float mx = fmaxf(fmaxf(smax[0], smax[1]), fmaxf(smax[2], smax[3]));
    float s = 0.f;
    if (tid       < NCHUNK) s += psum[(size_t)row*NCHUNK + tid]       * __expf(m0 - mx);
    if (tid + 256 < NCHUNK) s += psum[(size_t)row*NCHUNK + tid + 256] * __expf(m1 - mx);
    #pragma unroll
    for (int off = 1; off < 64; off <<= 1)
        s += __shfl_xor(s, off);
    if ((tid & 63) == 0) ssum[wave] = s;
    __syncthreads();
    if (tid == 0) {
        float st = ssum[0] + ssum[1] + ssum[2] + ssum[3];
        float lse = mx + logf(st);
        int tg = targets[row];
        rowloss[row] = (tg != 0) ? (lse - tlogit[row]) : 0.0f;
    }
}

// ---------------- final sum over rows ----------------
__global__ __launch_bounds__(256) void finalize_kernel(
    const float* __restrict__ rowloss, const int* __restrict__ targets,
    float* __restrict__ out)
{
    const int tid = threadIdx.x;
    float s = 0.f; float c = 0.f;
    for (int i = tid; i < NROWS; i += 256) {
        s += rowloss[i];
        c += (targets[i] != 0) ? 1.0f : 0.0f;
    }
    #pragma unroll
    for (int off = 1; off < 64; off <<= 1) {
        s += __shfl_xor(s, off);
        c += __shfl_xor(c, off);
    }
    __shared__ float ss[4], sc[4];
    const int wave = tid >> 6;
    if ((tid & 63) == 0) { ss[wave] = s; sc[wave] = c; }
    __syncthreads();
    if (tid == 0) {
        float st = ss[0]+ss[1]+ss[2]+ss[3];
        float ct = sc[0]+sc[1]+sc[2]+sc[3];
        out[0] = st / fmaxf(ct, 1.0f);
    }
}

extern "C" void kernel_launch(void* const* d_in, const int* in_sizes, int n_in,
                              void* d_out, int out_size, void* d_ws, size_t ws_size,
                              hipStream_t stream) {
    const float* h       = (const float*)d_in[0];   // (16,512,768) f32
    const int*   wid     = (const int*)  d_in[1];   // (16,512) i32
    const int*   targets = (const int*)  d_in[2];   // (16,256) i32
    const float* Wc      = (const float*)d_in[3];   // (768,32000) f32
    const float* bc      = (const float*)d_in[4];   // (32000,) f32
    float* out = (float*)d_out;

    unsigned char* pooled = (unsigned char*)d_ws;                // 4096*768 fp8
    unsigned char* Wt     = pooled + (size_t)NROWS*HH;           // 32000*768 fp8
    float* pmax  = (float*)(Wt + (size_t)HH*VV);                 // 4096*500
    float* psum  = pmax + (size_t)NROWS*NCHUNK;                  // 4096*500
    float* tlog  = psum + (size_t)NROWS*NCHUNK;                  // 4096
    float* rowl  = tlog + NROWS;                                 // 4096

    pool_kernel<<<NROWS, 256, 0, stream>>>(h, wid, (unsigned int*)pooled);
    wt_kernel<<<dim3(VV/64, HH/64), 256, 0, stream>>>(Wc, Wt);
    logits_kernel<<<NWG, 256, 0, stream>>>(
        pooled, Wt, bc, targets, pmax, psum, tlog);
    reduce_kernel<<<NROWS, 256, 0, stream>>>(pmax, psum, tlog, targets, rowl);
    finalize_kernel<<<1, 256, 0, stream>>>(rowl, targets, out);
}

// Round 12
// 689.995 us; speedup vs baseline: 1.8042x; 1.4911x over previous
//
#include <hip/hip_runtime.h>
#include <math.h>

#define BB 16
#define SS 512
#define HH 768
#define WW 256
#define VV 32000
#define NROWS (BB*WW)          // 4096
#define NCHUNK 500             // 64-wide v chunks
#define BM 128
#define BN 128
#define BK 64                  // fp8: 64 bytes per row per k-tile
#define NKT (HH/BK)            // 12
#define NMT (NROWS/BM)         // 32
#define NVT (VV/BN)            // 250
#define NWG (NMT*NVT)          // 8000
#define WSCALE 64.0f
#define WISCALE (1.0f/64.0f)

typedef __attribute__((ext_vector_type(8))) int i32x8;
typedef __attribute__((ext_vector_type(16))) float f32x16;

#define GLOAD16(g, l) __builtin_amdgcn_global_load_lds( \
    (const __attribute__((address_space(1))) void*)(g), \
    (__attribute__((address_space(3))) void*)(l), 16, 0, 0)

// pack 4 floats -> 4 fp8 e4m3 bytes (OCP)
__device__ __forceinline__ unsigned int pk4_fp8(float a0, float a1, float a2, float a3) {
    int r = __builtin_amdgcn_cvt_pk_fp8_f32(a0, a1, 0, false);
    r = __builtin_amdgcn_cvt_pk_fp8_f32(a2, a3, r, true);
    return (unsigned int)r;
}

// ---------------- pooling: one block per (b, w), fp8 output ----------------
// Stored layout: within each 16B slot, the two 8B halves are swapped when
// row bit3 is set (feeds the conflict-free LDS read swizzle).
__global__ __launch_bounds__(256) void pool_kernel(
    const float* __restrict__ h, const int* __restrict__ wid,
    unsigned int* __restrict__ pooled32)   // 4096 x 192 u32 (=768 fp8)
{
    int blk = blockIdx.x;
    int b = blk >> 8;
    int w = blk & 255;
    int tid = threadIdx.x;
    __shared__ int s_wid[SS];
    for (int i = tid; i < SS; i += 256) s_wid[i] = wid[b*SS + i];
    __syncthreads();
    int lo = 0, hi = SS;
    while (lo < hi) { int mid = (lo + hi) >> 1; if (s_wid[mid] < w) lo = mid + 1; else hi = mid; }
    int start = lo;
    hi = SS;
    while (lo < hi) { int mid = (lo + hi) >> 1; if (s_wid[mid] <= w) lo = mid + 1; else hi = mid; }
    int end = lo;
    int cnt = end - start;

    if (tid < 192) {
        float4 a = {0.f, 0.f, 0.f, 0.f};
        const float* hb = h + (size_t)b*SS*HH;
        for (int s = start; s < end; ++s) {
            float4 r = *(const float4*)&hb[(size_t)s*HH + tid*4];
            a.x += r.x; a.y += r.y; a.z += r.z; a.w += r.w;
        }
        float inv = (cnt > 0) ? (1.0f / (float)cnt) : 0.0f;
        int p = (blk >> 3) & 1;                 // row bit3 -> swap 8B halves
        pooled32[blk*192 + (tid ^ (p << 1))] = pk4_fp8(a.x*inv, a.y*inv, a.z*inv, a.w*inv);
    }
}

// ------- convert + transpose W: (768,32000) f32 -> (32000,768) fp8 (x64 scale) -------
// Same half-swap-by-row-bit3 storage as pooled.
__global__ __launch_bounds__(256) void wt_kernel(
    const float* __restrict__ Wc, unsigned char* __restrict__ Wt)
{
    const int v0 = blockIdx.x * 64;
    const int k0 = blockIdx.y * 64;
    const int t = threadIdx.x;
    __shared__ float S[64][65];
    #pragma unroll
    for (int j = 0; j < 4; ++j) {
        int idx = t + j*256;
        int kr = idx >> 4;
        int vs = idx & 15;
        float4 f = *(const float4*)&Wc[(size_t)(k0+kr)*VV + v0 + vs*4];
        S[kr][vs*4+0] = f.x; S[kr][vs*4+1] = f.y;
        S[kr][vs*4+2] = f.z; S[kr][vs*4+3] = f.w;
    }
    __syncthreads();
    #pragma unroll
    for (int j = 0; j < 2; ++j) {
        int idx = t + j*256;
        int vi = idx >> 3;     // 0..63 (row within tile)
        int ks = idx & 7;      // 0..7 (8B seg)
        float f[8];
        #pragma unroll
        for (int i = 0; i < 8; ++i) f[i] = S[ks*8+i][vi] * WSCALE;
        uint2 o;
        o.x = pk4_fp8(f[0], f[1], f[2], f[3]);
        o.y = pk4_fp8(f[4], f[5], f[6], f[7]);
        int p = (vi >> 3) & 1;                  // row bit3 -> swap 8B halves
        *(uint2*)&Wt[(size_t)(v0+vi)*HH + k0 + (ks ^ p)*8] = o;
    }
}

// ------- MX-fp8 MFMA GEMM (32x32x64 f8f6f4, unit scales), 128x128 tile -------
// 256 threads = 4 waves (2M x 2N), wave tile 64x64 = 2x2 frags of 32x32.
// launch_bounds(256,3): cap ~170 regs = 64 acc (AGPR half of unified file)
// + ~106 arch for fragments/addressing -> NO spill (R10/R11 died at the
// (256,4)=128 cap: 64 acc + 64 arch left fragments in scratch -> 1.9GB WRITE).
// LDS 2 dbuf x (8KB A + 8KB B) = 32 KB; 3 blocks/CU = 12 waves, 3 groups.
// Zero-conflict XOR LDS layout as R9. C/D: col = lane&31,
// row = (reg&3) + 8*(reg>>2) + 4*(lane>>5).
__global__ __launch_bounds__(256, 3) void logits_kernel(
    const unsigned char* __restrict__ Pb, const unsigned char* __restrict__ Wt,
    const float* __restrict__ bc, const int* __restrict__ targets,
    float* __restrict__ pmax, float* __restrict__ psum,
    float* __restrict__ tlogit)
{
    __shared__ unsigned char Alds[2][BM*BK];   // 2 x 8 KB
    __shared__ unsigned char Blds[2][BN*BK];   // 2 x 8 KB

    // XCD swizzle (NWG = 8000, divisible by 8), m-minor within XCD chunk
    const int id = blockIdx.x;
    const int wg = (id & 7) * (NWG/8) + (id >> 3);
    const int mt = wg % NMT;
    const int vt = wg / NMT;

    const int t = threadIdx.x;
    const int w = t >> 6;           // wave 0..3
    const int lane = t & 63;
    const int c31 = lane & 31;
    const int kg = lane >> 5;       // k-group 0..1
    const int wr = w >> 1;          // 0..1 (M)
    const int wc = w & 1;           // 0..1 (N)
    const int row0 = mt * BM;
    const int v0 = vt * BN;

    // staging: one call = 64 lanes x 16 B = 16 rows x 64 B; lane = rr*4 + s
    const int rr = lane >> 2;                     // 0..15 row within call
    const int sg = (lane & 3) ^ ((rr >> 1) & 3);  // pre-swizzled global 16B slot

    #define STAGE(BUF, KT) do {                                                   \
        const int k0_ = (KT) * BK;                                                \
        _Pragma("unroll")                                                         \
        for (int j_ = 0; j_ < 2; ++j_) {                                          \
            int ca_ = w*2 + j_;                                                   \
            GLOAD16(Pb + (size_t)(row0 + ca_*16 + rr)*HH + k0_ + sg*16,           \
                    &Alds[BUF][ca_*1024]);                                        \
            GLOAD16(Wt + (size_t)(v0 + ca_*16 + rr)*HH + k0_ + sg*16,             \
                    &Blds[BUF][ca_*1024]);                                        \
        }                                                                         \
    } while (0)

    f32x16 acc00 = (f32x16)(0.f), acc01 = (f32x16)(0.f);
    f32x16 acc10 = (f32x16)(0.f), acc11 = (f32x16)(0.f);

    STAGE(0, 0);
    __syncthreads();

    // register-only fragment load: 4x ds_read_b64 through the XOR layout
    #define LD_FRAG(DST, BASE, ROW) do {                                          \
        const int r_ = (ROW);                                                     \
        const int ro_ = r_ * BK;                                                  \
        const int s2_ = (r_ >> 1) & 3, s3_ = (r_ >> 3) & 1;                       \
        int2 q0_ = *(const int2*)((BASE) + ro_ + ((((kg*4+0)>>1)^s2_)<<4) + ((((kg*4+0)&1)^s3_)<<3)); \
        int2 q1_ = *(const int2*)((BASE) + ro_ + ((((kg*4+1)>>1)^s2_)<<4) + ((((kg*4+1)&1)^s3_)<<3)); \
        int2 q2_ = *(const int2*)((BASE) + ro_ + ((((kg*4+2)>>1)^s2_)<<4) + ((((kg*4+2)&1)^s3_)<<3)); \
        int2 q3_ = *(const int2*)((BASE) + ro_ + ((((kg*4+3)>>1)^s2_)<<4) + ((((kg*4+3)&1)^s3_)<<3)); \
        DST = (i32x8){q0_.x, q0_.y, q1_.x, q1_.y, q2_.x, q2_.y, q3_.x, q3_.y};    \
    } while (0)

    for (int kt = 0; kt < NKT; ++kt) {
        const int buf = kt & 1;
        if (kt + 1 < NKT) STAGE(buf ^ 1, kt + 1);

        const unsigned char* Ab = &Alds[buf][0];
        const unsigned char* Bb = &Blds[buf][0];

        i32x8 a0, a1, b0, b1;
        LD_FRAG(a0, Ab, wr*64 + c31);
        LD_FRAG(a1, Ab, wr*64 + 32 + c31);
        LD_FRAG(b0, Bb, wc*64 + c31);
        acc00 = __builtin_amdgcn_mfma_scale_f32_32x32x64_f8f6f4(
            a0, b0, acc00, 0, 0, 0, 0x7F7F7F7F, 0, 0x7F7F7F7F);
        acc10 = __builtin_amdgcn_mfma_scale_f32_32x32x64_f8f6f4(
            a1, b0, acc10, 0, 0, 0, 0x7F7F7F7F, 0, 0x7F7F7F7F);
        LD_FRAG(b1, Bb, wc*64 + 32 + c31);
        acc01 = __builtin_amdgcn_mfma_scale_f32_32x32x64_f8f6f4(
            a0, b1, acc01, 0, 0, 0, 0x7F7F7F7F, 0, 0x7F7F7F7F);
        acc11 = __builtin_amdgcn_mfma_scale_f32_32x32x64_f8f6f4(
            a1, b1, acc11, 0, 0, 0, 0x7F7F7F7F, 0, 0x7F7F7F7F);

        __syncthreads();
    }

    // epilogue: unscale + bias + per-row max/sumexp over this wave's 64 cols
    const int cchunk = vt*2 + wc;
    float bias0 = bc[v0 + wc*64 + c31];
    float bias1 = bc[v0 + wc*64 + 32 + c31];

    #define EPILOG(ACCL, ACCR, MF) do {                                           \
        _Pragma("unroll")                                                         \
        for (int r = 0; r < 16; ++r) {                                            \
            const int row = row0 + wr*64 + (MF)*32 + (r & 3) + 8*(r >> 2) + 4*kg; \
            float va = (ACCL)[r]*WISCALE + bias0;                                 \
            float vb = (ACCR)[r]*WISCALE + bias1;                                 \
            float mx = fmaxf(va, vb);                                             \
            _Pragma("unroll")                                                     \
            for (int off = 1; off < 32; off <<= 1)                                \
                mx = fmaxf(mx, __shfl_xor(mx, off, 32));                          \
            float se = __expf(va - mx) + __expf(vb - mx);                         \
            _Pragma("unroll")                                                     \
            for (int off = 1; off < 32; off <<= 1)                                \
                se += __shfl_xor(se, off, 32);                                    \
            if (c31 == 0) {                                                       \
                pmax[(size_t)row*NCHUNK + cchunk] = mx;                           \
                psum[(size_t)row*NCHUNK + cchunk] = se;                           \
            }                                                                     \
            int tg = targets[row];                                                \
            if (tg == v0 + wc*64 + c31)           tlogit[row] = va;               \
            else if (tg == v0 + wc*64 + 32 + c31) tlogit[row] = vb;               \
        }                                                                         \
    } while (0)

    EPILOG(acc00, acc01, 0);
    EPILOG(acc10, acc11, 1);
}

// ---------------- combine chunk partials -> per-row loss ----------------
__global__ __launch_bounds__(256) void reduce_kernel(
    const float* __restrict__ pmax, const float* __restrict__ psum,
    const float* __restrict__ tlogit, const int* __restrict__ targets,
    float* __restrict__ rowloss)
{
    const int row = blockIdx.x;
    const int tid = threadIdx.x;
    float m0 = (tid       < NCHUNK) ? pmax[(size_t)row*NCHUNK + tid]       : -INFINITY;
    float m1 = (tid + 256 < NCHUNK) ? pmax[(size_t)row*NCHUNK + tid + 256] : -INFINITY;
    float mw = fmaxf(m0, m1);
    #pragma unroll
    for (int off = 1; off < 64; off <<= 1)
        mw = fmaxf(mw, __shfl_xor(mw, off));
    __shared__ float smax[4];
    __shared__ float ssum[4];
    const int wave = tid >> 6;
    if ((tid & 63) == 0) smax[wave] = mw;
    __syncthreads();
    float mx = fmaxf(fmaxf(smax[0], smax[1]), fmaxf(smax[2], smax[3]));
    float s = 0.f;
    if (tid       < NCHUNK) s += psum[(size_t)row*NCHUNK + tid]       * __expf(m0 - mx);
    if (tid + 256 < NCHUNK) s += psum[(size_t)row*NCHUNK + tid + 256] * __expf(m1 - mx);
    #pragma unroll
    for (int off = 1; off < 64; off <<= 1)
        s += __shfl_xor(s, off);
    if ((tid & 63) == 0) ssum[wave] = s;
    __syncthreads();
    if (tid == 0) {
        float st = ssum[0] + ssum[1] + ssum[2] + ssum[3];
        float lse = mx + logf(st);
        int tg = targets[row];
        rowloss[row] = (tg != 0) ? (lse - tlogit[row]) : 0.0f;
    }
}

// ---------------- final sum over rows ----------------
__global__ __launch_bounds__(256) void finalize_kernel(
    const float* __restrict__ rowloss, const int* __restrict__ targets,
    float* __restrict__ out)
{
    const int tid = threadIdx.x;
    float s = 0.f; float c = 0.f;
    for (int i = tid; i < NROWS; i += 256) {
        s += rowloss[i];
        c += (targets[i] != 0) ? 1.0f : 0.0f;
    }
    #pragma unroll
    for (int off = 1; off < 64; off <<= 1) {
        s += __shfl_xor(s, off);
        c += __shfl_xor(c, off);
    }
    __shared__ float ss[4], sc[4];
    const int wave = tid >> 6;
    if ((tid & 63) == 0) { ss[wave] = s; sc[wave] = c; }
    __syncthreads();
    if (tid == 0) {
        float st = ss[0]+ss[1]+ss[2]+ss[3];
        float ct = sc[0]+sc[1]+sc[2]+sc[3];
        out[0] = st / fmaxf(ct, 1.0f);
    }
}

extern "C" void kernel_launch(void* const* d_in, const int* in_sizes, int n_in,
                              void* d_out, int out_size, void* d_ws, size_t ws_size,
                              hipStream_t stream) {
    const float* h       = (const float*)d_in[0];   // (16,512,768) f32
    const int*   wid     = (const int*)  d_in[1];   // (16,512) i32
    const int*   targets = (const int*)  d_in[2];   // (16,256) i32
    const float* Wc      = (const float*)d_in[3];   // (768,32000) f32
    const float* bc      = (const float*)d_in[4];   // (32000,) f32
    float* out = (float*)d_out;

    unsigned char* pooled = (unsigned char*)d_ws;                // 4096*768 fp8
    unsigned char* Wt     = pooled + (size_t)NROWS*HH;           // 32000*768 fp8
    float* pmax  = (float*)(Wt + (size_t)HH*VV);                 // 4096*500
    float* psum  = pmax + (size_t)NROWS*NCHUNK;                  // 4096*500
    float* tlog  = psum + (size_t)NROWS*NCHUNK;                  // 4096
    float* rowl  = tlog + NROWS;                                 // 4096

    pool_kernel<<<NROWS, 256, 0, stream>>>(h, wid, (unsigned int*)pooled);
    wt_kernel<<<dim3(VV/64, HH/64), 256, 0, stream>>>(Wc, Wt);
    logits_kernel<<<NWG, 256, 0, stream>>>(
        pooled, Wt, bc, targets, pmax, psum, tlog);
    reduce_kernel<<<NROWS, 256, 0, stream>>>(pmax, psum, tlog, targets, rowl);
    finalize_kernel<<<1, 256, 0, stream>>>(rowl, targets, out);
}

// Round 13
// 304.710 us; speedup vs baseline: 4.0855x; 2.2644x over previous
//
#include <hip/hip_runtime.h>
#include <math.h>

#define BB 16
#define SS 512
#define HH 768
#define WW 256
#define VV 32000
#define NROWS (BB*WW)          // 4096
#define NCHUNK 500             // 64-wide v chunks
#define BM 64
#define BN 128
#define BK 64                  // fp8: 64 bytes per row per k-tile
#define NKT (HH/BK)            // 12
#define NMT (NROWS/BM)         // 64
#define NVT (VV/BN)            // 250
#define NWG (NMT*NVT)          // 16000
#define WSCALE 64.0f
#define WISCALE (1.0f/64.0f)

typedef __attribute__((ext_vector_type(8))) int i32x8;
typedef __attribute__((ext_vector_type(16))) float f32x16;

#define GLOAD16(g, l) __builtin_amdgcn_global_load_lds( \
    (const __attribute__((address_space(1))) void*)(g), \
    (__attribute__((address_space(3))) void*)(l), 16, 0, 0)

// pack 4 floats -> 4 fp8 e4m3 bytes (OCP)
__device__ __forceinline__ unsigned int pk4_fp8(float a0, float a1, float a2, float a3) {
    int r = __builtin_amdgcn_cvt_pk_fp8_f32(a0, a1, 0, false);
    r = __builtin_amdgcn_cvt_pk_fp8_f32(a2, a3, r, true);
    return (unsigned int)r;
}

// ---------------- pooling: one block per (b, w), fp8 output ----------------
// Stored layout: within each 16B slot, the two 8B halves are swapped when
// row bit3 is set (feeds the conflict-free LDS read swizzle).
__global__ __launch_bounds__(256) void pool_kernel(
    const float* __restrict__ h, const int* __restrict__ wid,
    unsigned int* __restrict__ pooled32)   // 4096 x 192 u32 (=768 fp8)
{
    int blk = blockIdx.x;
    int b = blk >> 8;
    int w = blk & 255;
    int tid = threadIdx.x;
    __shared__ int s_wid[SS];
    for (int i = tid; i < SS; i += 256) s_wid[i] = wid[b*SS + i];
    __syncthreads();
    int lo = 0, hi = SS;
    while (lo < hi) { int mid = (lo + hi) >> 1; if (s_wid[mid] < w) lo = mid + 1; else hi = mid; }
    int start = lo;
    hi = SS;
    while (lo < hi) { int mid = (lo + hi) >> 1; if (s_wid[mid] <= w) lo = mid + 1; else hi = mid; }
    int end = lo;
    int cnt = end - start;

    if (tid < 192) {
        float4 a = {0.f, 0.f, 0.f, 0.f};
        const float* hb = h + (size_t)b*SS*HH;
        for (int s = start; s < end; ++s) {
            float4 r = *(const float4*)&hb[(size_t)s*HH + tid*4];
            a.x += r.x; a.y += r.y; a.z += r.z; a.w += r.w;
        }
        float inv = (cnt > 0) ? (1.0f / (float)cnt) : 0.0f;
        int p = (blk >> 3) & 1;                 // row bit3 -> swap 8B halves
        pooled32[blk*192 + (tid ^ (p << 1))] = pk4_fp8(a.x*inv, a.y*inv, a.z*inv, a.w*inv);
    }
}

// ------- convert + transpose W: (768,32000) f32 -> (32000,768) fp8 (x64 scale) -------
// Same half-swap-by-row-bit3 storage as pooled.
__global__ __launch_bounds__(256) void wt_kernel(
    const float* __restrict__ Wc, unsigned char* __restrict__ Wt)
{
    const int v0 = blockIdx.x * 64;
    const int k0 = blockIdx.y * 64;
    const int t = threadIdx.x;
    __shared__ float S[64][65];
    #pragma unroll
    for (int j = 0; j < 4; ++j) {
        int idx = t + j*256;
        int kr = idx >> 4;
        int vs = idx & 15;
        float4 f = *(const float4*)&Wc[(size_t)(k0+kr)*VV + v0 + vs*4];
        S[kr][vs*4+0] = f.x; S[kr][vs*4+1] = f.y;
        S[kr][vs*4+2] = f.z; S[kr][vs*4+3] = f.w;
    }
    __syncthreads();
    #pragma unroll
    for (int j = 0; j < 2; ++j) {
        int idx = t + j*256;
        int vi = idx >> 3;     // 0..63 (row within tile)
        int ks = idx & 7;      // 0..7 (8B seg)
        float f[8];
        #pragma unroll
        for (int i = 0; i < 8; ++i) f[i] = S[ks*8+i][vi] * WSCALE;
        uint2 o;
        o.x = pk4_fp8(f[0], f[1], f[2], f[3]);
        o.y = pk4_fp8(f[4], f[5], f[6], f[7]);
        int p = (vi >> 3) & 1;                  // row bit3 -> swap 8B halves
        *(uint2*)&Wt[(size_t)(v0+vi)*HH + k0 + (ks ^ p)*8] = o;
    }
}

// ------- MX-fp8 MFMA GEMM (32x32x64 f8f6f4, unit scales), 64x128 tile -------
// 256 threads = 4 waves (2M x 2N), wave tile 32x64 = 1x2 frags of 32x32.
// Accumulator = ONLY 2x f32x16 (32 regs) -- the 64-reg acc of R10-12 could not
// be allocated spill-free (alignment fragmentation); this shape needs ~90 regs
// total and fits (256,4)=128 with margin. B-frags loaded one-at-a-time.
// LDS 2 dbuf x (A 4KB + B 8KB) = 24 KB -> 4 blocks/CU, 4 indep barrier groups.
// Zero-conflict XOR LDS layout (verified BANK_CONFLICT=0 in R10-12).
// C/D: col = lane&31, row = (reg&3) + 8*(reg>>2) + 4*(lane>>5).
__global__ __launch_bounds__(256, 4) void logits_kernel(
    const unsigned char* __restrict__ Pb, const unsigned char* __restrict__ Wt,
    const float* __restrict__ bc, const int* __restrict__ targets,
    float* __restrict__ pmax, float* __restrict__ psum,
    float* __restrict__ tlogit)
{
    __shared__ unsigned char Alds[2][BM*BK];   // 2 x 4 KB
    __shared__ unsigned char Blds[2][BN*BK];   // 2 x 8 KB

    // XCD swizzle (NWG = 16000, divisible by 8), m-minor within XCD chunk
    const int id = blockIdx.x;
    const int wg = (id & 7) * (NWG/8) + (id >> 3);
    const int mt = wg % NMT;
    const int vt = wg / NMT;

    const int t = threadIdx.x;
    const int w = t >> 6;           // wave 0..3
    const int lane = t & 63;
    const int c31 = lane & 31;
    const int kg = lane >> 5;       // k-group 0..1
    const int wr = w >> 1;          // 0..1 (M)
    const int wc = w & 1;           // 0..1 (N)
    const int row0 = mt * BM;
    const int v0 = vt * BN;

    // staging: one call = 64 lanes x 16 B = 16 rows x 64 B; lane = rr*4 + s
    const int rr = lane >> 2;                     // 0..15 row within call
    const int sg = (lane & 3) ^ ((rr >> 1) & 3);  // pre-swizzled global 16B slot

    // A: 4 calls (1/wave), B: 8 calls (2/wave) -> 3 loads/thread per STAGE
    #define STAGE(BUF, KT) do {                                                   \
        const int k0_ = (KT) * BK;                                                \
        GLOAD16(Pb + (size_t)(row0 + w*16 + rr)*HH + k0_ + sg*16,                 \
                &Alds[BUF][w*1024]);                                              \
        _Pragma("unroll")                                                         \
        for (int j_ = 0; j_ < 2; ++j_) {                                          \
            int cb_ = w*2 + j_;                                                   \
            GLOAD16(Wt + (size_t)(v0 + cb_*16 + rr)*HH + k0_ + sg*16,             \
                    &Blds[BUF][cb_*1024]);                                        \
        }                                                                         \
    } while (0)

    f32x16 acc0 = (f32x16)(0.f), acc1 = (f32x16)(0.f);

    STAGE(0, 0);
    __syncthreads();

    // register-only fragment load: 4x ds_read_b64 through the XOR layout
    #define LD_FRAG(DST, BASE, ROW) do {                                          \
        const int r_ = (ROW);                                                     \
        const int ro_ = r_ * BK;                                                  \
        const int s2_ = (r_ >> 1) & 3, s3_ = (r_ >> 3) & 1;                       \
        int2 q0_ = *(const int2*)((BASE) + ro_ + ((((kg*4+0)>>1)^s2_)<<4) + ((((kg*4+0)&1)^s3_)<<3)); \
        int2 q1_ = *(const int2*)((BASE) + ro_ + ((((kg*4+1)>>1)^s2_)<<4) + ((((kg*4+1)&1)^s3_)<<3)); \
        int2 q2_ = *(const int2*)((BASE) + ro_ + ((((kg*4+2)>>1)^s2_)<<4) + ((((kg*4+2)&1)^s3_)<<3)); \
        int2 q3_ = *(const int2*)((BASE) + ro_ + ((((kg*4+3)>>1)^s2_)<<4) + ((((kg*4+3)&1)^s3_)<<3)); \
        DST = (i32x8){q0_.x, q0_.y, q1_.x, q1_.y, q2_.x, q2_.y, q3_.x, q3_.y};    \
    } while (0)

    for (int kt = 0; kt < NKT; ++kt) {
        const int buf = kt & 1;
        if (kt + 1 < NKT) STAGE(buf ^ 1, kt + 1);

        const unsigned char* Ab = &Alds[buf][0];
        const unsigned char* Bb = &Blds[buf][0];

        i32x8 a0, b0, b1;
        LD_FRAG(a0, Ab, wr*32 + c31);
        LD_FRAG(b0, Bb, wc*64 + c31);
        acc0 = __builtin_amdgcn_mfma_scale_f32_32x32x64_f8f6f4(
            a0, b0, acc0, 0, 0, 0, 0x7F7F7F7F, 0, 0x7F7F7F7F);
        LD_FRAG(b1, Bb, wc*64 + 32 + c31);
        acc1 = __builtin_amdgcn_mfma_scale_f32_32x32x64_f8f6f4(
            a0, b1, acc1, 0, 0, 0, 0x7F7F7F7F, 0, 0x7F7F7F7F);

        __syncthreads();
    }

    // epilogue: unscale + bias + per-row max/sumexp over this wave's 64 cols
    const int cchunk = vt*2 + wc;
    float bias0 = bc[v0 + wc*64 + c31];
    float bias1 = bc[v0 + wc*64 + 32 + c31];

    #pragma unroll
    for (int r = 0; r < 16; ++r) {
        const int row = row0 + wr*32 + (r & 3) + 8*(r >> 2) + 4*kg;
        float va = acc0[r]*WISCALE + bias0;
        float vb = acc1[r]*WISCALE + bias1;
        float mx = fmaxf(va, vb);
        #pragma unroll
        for (int off = 1; off < 32; off <<= 1)
            mx = fmaxf(mx, __shfl_xor(mx, off, 32));
        float se = __expf(va - mx) + __expf(vb - mx);
        #pragma unroll
        for (int off = 1; off < 32; off <<= 1)
            se += __shfl_xor(se, off, 32);
        if (c31 == 0) {
            pmax[(size_t)row*NCHUNK + cchunk] = mx;
            psum[(size_t)row*NCHUNK + cchunk] = se;
        }
        int tg = targets[row];
        if (tg == v0 + wc*64 + c31)           tlogit[row] = va;
        else if (tg == v0 + wc*64 + 32 + c31) tlogit[row] = vb;
    }
}

// ---------------- combine chunk partials -> per-row loss ----------------
__global__ __launch_bounds__(256) void reduce_kernel(
    const float* __restrict__ pmax, const float* __restrict__ psum,
    const float* __restrict__ tlogit, const int* __restrict__ targets,
    float* __restrict__ rowloss)
{
    const int row = blockIdx.x;
    const int tid = threadIdx.x;
    float m0 = (tid       < NCHUNK) ? pmax[(size_t)row*NCHUNK + tid]       : -INFINITY;
    float m1 = (tid + 256 < NCHUNK) ? pmax[(size_t)row*NCHUNK + tid + 256] : -INFINITY;
    float mw = fmaxf(m0, m1);
    #pragma unroll
    for (int off = 1; off < 64; off <<= 1)
        mw = fmaxf(mw, __shfl_xor(mw, off));
    __shared__ float smax[4];
    __shared__ float ssum[4];
    const int wave = tid >> 6;
    if ((tid & 63) == 0) smax[wave] = mw;
    __syncthreads();
    float mx = fmaxf(fmaxf(smax[0], smax[1]), fmaxf(smax[2], smax[3]));
    float s = 0.f;
    if (tid       < NCHUNK) s += psum[(size_t)row*NCHUNK + tid]       * __expf(m0 - mx);
    if (tid + 256 < NCHUNK) s += psum[(size_t)row*NCHUNK + tid + 256] * __expf(m1 - mx);
    #pragma unroll
    for (int off = 1; off < 64; off <<= 1)
        s += __shfl_xor(s, off);
    if ((tid & 63) == 0) ssum[wave] = s;
    __syncthreads();
    if (tid == 0) {
        float st = ssum[0] + ssum[1] + ssum[2] + ssum[3];
        float lse = mx + logf(st);
        int tg = targets[row];
        rowloss[row] = (tg != 0) ? (lse - tlogit[row]) : 0.0f;
    }
}

// ---------------- final sum over rows ----------------
__global__ __launch_bounds__(256) void finalize_kernel(
    const float* __restrict__ rowloss, const int* __restrict__ targets,
    float* __restrict__ out)
{
    const int tid = threadIdx.x;
    float s = 0.f; float c = 0.f;
    for (int i = tid; i < NROWS; i += 256) {
        s += rowloss[i];
        c += (targets[i] != 0) ? 1.0f : 0.0f;
    }
    #pragma unroll
    for (int off = 1; off < 64; off <<= 1) {
        s += __shfl_xor(s, off);
        c += __shfl_xor(c, off);
    }
    __shared__ float ss[4], sc[4];
    const int wave = tid >> 6;
    if ((tid & 63) == 0) { ss[wave] = s; sc[wave] = c; }
    __syncthreads();
    if (tid == 0) {
        float st = ss[0]+ss[1]+ss[2]+ss[3];
        float ct = sc[0]+sc[1]+sc[2]+sc[3];
        out[0] = st / fmaxf(ct, 1.0f);
    }
}

extern "C" void kernel_launch(void* const* d_in, const int* in_sizes, int n_in,
                              void* d_out, int out_size, void* d_ws, size_t ws_size,
                              hipStream_t stream) {
    const float* h       = (const float*)d_in[0];   // (16,512,768) f32
    const int*   wid     = (const int*)  d_in[1];   // (16,512) i32
    const int*   targets = (const int*)  d_in[2];   // (16,256) i32
    const float* Wc      = (const float*)d_in[3];   // (768,32000) f32
    const float* bc      = (const float*)d_in[4];   // (32000,) f32
    float* out = (float*)d_out;

    unsigned char* pooled = (unsigned char*)d_ws;                // 4096*768 fp8
    unsigned char* Wt     = pooled + (size_t)NROWS*HH;           // 32000*768 fp8
    float* pmax  = (float*)(Wt + (size_t)HH*VV);                 // 4096*500
    float* psum  = pmax + (size_t)NROWS*NCHUNK;                  // 4096*500
    float* tlog  = psum + (size_t)NROWS*NCHUNK;                  // 4096
    float* rowl  = tlog + NROWS;                                 // 4096

    pool_kernel<<<NROWS, 256, 0, stream>>>(h, wid, (unsigned int*)pooled);
    wt_kernel<<<dim3(VV/64, HH/64), 256, 0, stream>>>(Wc, Wt);
    logits_kernel<<<NWG, 256, 0, stream>>>(
        pooled, Wt, bc, targets, pmax, psum, tlog);
    reduce_kernel<<<NROWS, 256, 0, stream>>>(pmax, psum, tlog, targets, rowl);
    finalize_kernel<<<1, 256, 0, stream>>>(rowl, targets, out);
}

// Round 14
// 254.855 us; speedup vs baseline: 4.8848x; 1.1956x over previous
//
#include <hip/hip_runtime.h>
#include <math.h>

#define BB 16
#define SS 512
#define HH 768
#define WW 256
#define VV 32000
#define NROWS (BB*WW)          // 4096
#define NCHUNK 500             // 64-wide v chunks
#define BM 128
#define BN 128
#define BK 64                  // fp8: 64 bytes per row per k-tile
#define NKT (HH/BK)            // 12
#define NBUF 3
#define NMT (NROWS/BM)         // 32
#define NVT (VV/BN)            // 250
#define NWG (NMT*NVT)          // 8000
#define WSCALE 64.0f
#define WISCALE (1.0f/64.0f)

typedef __attribute__((ext_vector_type(4))) float f32x4;

#define GLOAD16(g, l) __builtin_amdgcn_global_load_lds( \
    (const __attribute__((address_space(1))) void*)(g), \
    (__attribute__((address_space(3))) void*)(l), 16, 0, 0)

// pack 4 floats -> 4 fp8 e4m3 bytes (OCP)
__device__ __forceinline__ unsigned int pk4_fp8(float a0, float a1, float a2, float a3) {
    int r = __builtin_amdgcn_cvt_pk_fp8_f32(a0, a1, 0, false);
    r = __builtin_amdgcn_cvt_pk_fp8_f32(a2, a3, r, true);
    return (unsigned int)r;
}

// ---------------- pooling: one block per (b, w), fp8 output ----------------
// Stored layout: within each 16B slot, the two 8B halves are swapped when
// row bit3 is set (feeds the conflict-free LDS read swizzle).
__global__ __launch_bounds__(256) void pool_kernel(
    const float* __restrict__ h, const int* __restrict__ wid,
    unsigned int* __restrict__ pooled32)   // 4096 x 192 u32 (=768 fp8)
{
    int blk = blockIdx.x;
    int b = blk >> 8;
    int w = blk & 255;
    int tid = threadIdx.x;
    __shared__ int s_wid[SS];
    for (int i = tid; i < SS; i += 256) s_wid[i] = wid[b*SS + i];
    __syncthreads();
    int lo = 0, hi = SS;
    while (lo < hi) { int mid = (lo + hi) >> 1; if (s_wid[mid] < w) lo = mid + 1; else hi = mid; }
    int start = lo;
    hi = SS;
    while (lo < hi) { int mid = (lo + hi) >> 1; if (s_wid[mid] <= w) lo = mid + 1; else hi = mid; }
    int end = lo;
    int cnt = end - start;

    if (tid < 192) {
        float4 a = {0.f, 0.f, 0.f, 0.f};
        const float* hb = h + (size_t)b*SS*HH;
        for (int s = start; s < end; ++s) {
            float4 r = *(const float4*)&hb[(size_t)s*HH + tid*4];
            a.x += r.x; a.y += r.y; a.z += r.z; a.w += r.w;
        }
        float inv = (cnt > 0) ? (1.0f / (float)cnt) : 0.0f;
        int p = (blk >> 3) & 1;                 // row bit3 -> swap 8B halves
        pooled32[blk*192 + (tid ^ (p << 1))] = pk4_fp8(a.x*inv, a.y*inv, a.z*inv, a.w*inv);
    }
}

// ------- convert + transpose W: (768,32000) f32 -> (32000,768) fp8 (x64 scale) -------
// Same half-swap-by-row-bit3 storage as pooled.
__global__ __launch_bounds__(256) void wt_kernel(
    const float* __restrict__ Wc, unsigned char* __restrict__ Wt)
{
    const int v0 = blockIdx.x * 64;
    const int k0 = blockIdx.y * 64;
    const int t = threadIdx.x;
    __shared__ float S[64][65];
    #pragma unroll
    for (int j = 0; j < 4; ++j) {
        int idx = t + j*256;
        int kr = idx >> 4;
        int vs = idx & 15;
        float4 f = *(const float4*)&Wc[(size_t)(k0+kr)*VV + v0 + vs*4];
        S[kr][vs*4+0] = f.x; S[kr][vs*4+1] = f.y;
        S[kr][vs*4+2] = f.z; S[kr][vs*4+3] = f.w;
    }
    __syncthreads();
    #pragma unroll
    for (int j = 0; j < 2; ++j) {
        int idx = t + j*256;
        int vi = idx >> 3;     // 0..63 (row within tile)
        int ks = idx & 7;      // 0..7 (8B seg)
        float f[8];
        #pragma unroll
        for (int i = 0; i < 8; ++i) f[i] = S[ks*8+i][vi] * WSCALE;
        uint2 o;
        o.x = pk4_fp8(f[0], f[1], f[2], f[3]);
        o.y = pk4_fp8(f[4], f[5], f[6], f[7]);
        int p = (vi >> 3) & 1;                  // row bit3 -> swap 8B halves
        *(uint2*)&Wt[(size_t)(v0+vi)*HH + k0 + (ks ^ p)*8] = o;
    }
}

// ---------------- fp8 MFMA GEMM, 128x128, 3-buffer counted-vmcnt ----------------
// R9 geometry (proven: 0 conflicts, no spill) + R4 schedule (proven correct):
// 256 threads = 4 waves (2M x 2N), wave tile 64x64, BK=64.
// LDS: 3 buf x (A 8KB + B 8KB) = 48 KB -> 3 blocks/CU; launch_bounds(256,3).
// Depth-2 prefetch, fully unrolled k-loop: per step
//   vmcnt(4) [own loads for kt; kt+1's stay in flight; 0 only at tail]
//   -> s_barrier -> STAGE(kt+2) -> ds_read + MFMA.
// WAR: buf[(kt+2)%3] last read at kt-1; stage issued after barrier(kt) ✓.
// Swizzle: 16B slot s of row r holds global slot s^((r>>1)&3); global storage
// pre-swaps 8B halves by row bit3; read offset covers all 4 r16 bits -> 0 conflicts.
__global__ __launch_bounds__(256, 3) void logits_kernel(
    const unsigned char* __restrict__ Pb, const unsigned char* __restrict__ Wt,
    const float* __restrict__ bc, const int* __restrict__ targets,
    float* __restrict__ pmax, float* __restrict__ psum,
    float* __restrict__ tlogit)
{
    __shared__ unsigned char Alds[NBUF][BM*BK];   // 3 x 8 KB
    __shared__ unsigned char Blds[NBUF][BN*BK];   // 3 x 8 KB

    // XCD swizzle (NWG = 8000, divisible by 8), m-minor within XCD chunk
    const int id = blockIdx.x;
    const int wg = (id & 7) * (NWG/8) + (id >> 3);
    const int mt = wg % NMT;
    const int vt = wg / NMT;

    const int t = threadIdx.x;
    const int w = t >> 6;           // wave 0..3
    const int lane = t & 63;
    const int r16 = lane & 15;
    const int kb = lane >> 4;       // 0..3 (8-byte k-seg within 32)
    const int wr = w >> 1;          // 0..1 (M)
    const int wc = w & 1;           // 0..1 (N)
    const int row0 = mt * BM;
    const int v0 = vt * BN;

    // staging: one call = 64 lanes x 16 B = 16 rows x 64 B; lane = rr*4 + s
    const int rr = lane >> 2;                     // 0..15 row within call
    const int sg = (lane & 3) ^ ((rr >> 1) & 3);  // pre-swizzled global 16B slot

    // A: 8 calls (2/wave), B: 8 calls (2/wave) -> 4 loads/thread per STAGE
    #define STAGE(BUF, KT) do {                                                   \
        const int k0_ = (KT) * BK;                                                \
        _Pragma("unroll")                                                         \
        for (int j_ = 0; j_ < 2; ++j_) {                                          \
            int ca_ = w*2 + j_;                                                   \
            GLOAD16(Pb + (size_t)(row0 + ca_*16 + rr)*HH + k0_ + sg*16,           \
                    &Alds[BUF][ca_*1024]);                                        \
            GLOAD16(Wt + (size_t)(v0 + ca_*16 + rr)*HH + k0_ + sg*16,             \
                    &Blds[BUF][ca_*1024]);                                        \
        }                                                                         \
    } while (0)

    f32x4 acc[4][4];
    #pragma unroll
    for (int mf = 0; mf < 4; ++mf)
        #pragma unroll
        for (int nf = 0; nf < 4; ++nf)
            acc[mf][nf] = (f32x4){0.f, 0.f, 0.f, 0.f};

    STAGE(0, 0);
    STAGE(1, 1);

    const int swz2 = (r16 >> 1) & 3;
    const int swz3 = (r16 >> 3) & 1;

    #pragma unroll
    for (int kt = 0; kt < NKT; ++kt) {
        const int buf = kt % NBUF;

        // wait own 4 loads for tile kt (kt+1's 4 remain in flight), then sync
        if (kt + 1 < NKT) { asm volatile("s_waitcnt vmcnt(4)" ::: "memory"); }
        else              { asm volatile("s_waitcnt vmcnt(0)" ::: "memory"); }
        __builtin_amdgcn_s_barrier();
        asm volatile("" ::: "memory");

        // prefetch tile kt+2 into the buffer last read at kt-1 (safe post-barrier)
        if (kt + 2 < NKT) STAGE((kt + 2) % NBUF, kt + 2);

        long af[4][2], bfv[4][2];
        #pragma unroll
        for (int ks = 0; ks < 2; ++ks) {
            const int idx8 = ks*4 + kb;                       // 0..7
            const int off = (((idx8 >> 1) ^ swz2) << 4) | (((idx8 & 1) ^ swz3) << 3);
            #pragma unroll
            for (int mf = 0; mf < 4; ++mf)
                af[mf][ks] = *(const long*)&Alds[buf][(wr*64 + mf*16 + r16)*BK + off];
            #pragma unroll
            for (int nf = 0; nf < 4; ++nf)
                bfv[nf][ks] = *(const long*)&Blds[buf][(wc*64 + nf*16 + r16)*BK + off];
        }

        #pragma unroll
        for (int ks = 0; ks < 2; ++ks)
            #pragma unroll
            for (int mf = 0; mf < 4; ++mf)
                #pragma unroll
                for (int nf = 0; nf < 4; ++nf)
                    acc[mf][nf] = __builtin_amdgcn_mfma_f32_16x16x32_fp8_fp8(
                        af[mf][ks], bfv[nf][ks], acc[mf][nf], 0, 0, 0);
    }

    // epilogue: unscale + bias + per-row max/sumexp over this wave's 64 cols
    const int cchunk = vt*2 + wc;
    float bias[4];
    #pragma unroll
    for (int nf = 0; nf < 4; ++nf) bias[nf] = bc[v0 + wc*64 + nf*16 + r16];

    #pragma unroll
    for (int mf = 0; mf < 4; ++mf) {
        #pragma unroll
        for (int j = 0; j < 4; ++j) {
            const int row = row0 + wr*64 + mf*16 + kb*4 + j;
            float v[4]; float mx = -INFINITY;
            #pragma unroll
            for (int nf = 0; nf < 4; ++nf) {
                v[nf] = acc[mf][nf][j]*WISCALE + bias[nf];
                mx = fmaxf(mx, v[nf]);
            }
            #pragma unroll
            for (int off = 1; off < 16; off <<= 1)
                mx = fmaxf(mx, __shfl_xor(mx, off, 16));
            float se = 0.f;
            #pragma unroll
            for (int nf = 0; nf < 4; ++nf) se += __expf(v[nf] - mx);
            #pragma unroll
            for (int off = 1; off < 16; off <<= 1)
                se += __shfl_xor(se, off, 16);
            if (r16 == 0) {
                pmax[(size_t)row*NCHUNK + cchunk] = mx;
                psum[(size_t)row*NCHUNK + cchunk] = se;
            }
            int tg = targets[row];
            int base = v0 + wc*64 + r16;
            #pragma unroll
            for (int nf = 0; nf < 4; ++nf)
                if (tg == base + nf*16) tlogit[row] = v[nf];
        }
    }
}

// ---------------- combine chunk partials -> per-row loss ----------------
__global__ __launch_bounds__(256) void reduce_kernel(
    const float* __restrict__ pmax, const float* __restrict__ psum,
    const float* __restrict__ tlogit, const int* __restrict__ targets,
    float* __restrict__ rowloss)
{
    const int row = blockIdx.x;
    const int tid = threadIdx.x;
    float m0 = (tid       < NCHUNK) ? pmax[(size_t)row*NCHUNK + tid]       : -INFINITY;
    float m1 = (tid + 256 < NCHUNK) ? pmax[(size_t)row*NCHUNK + tid + 256] : -INFINITY;
    float mw = fmaxf(m0, m1);
    #pragma unroll
    for (int off = 1; off < 64; off <<= 1)
        mw = fmaxf(mw, __shfl_xor(mw, off));
    __shared__ float smax[4];
    __shared__ float ssum[4];
    const int wave = tid >> 6;
    if ((tid & 63) == 0) smax[wave] = mw;
    __syncthreads();
    float mx = fmaxf(fmaxf(smax[0], smax[1]), fmaxf(smax[2], smax[3]));
    float s = 0.f;
    if (tid       < NCHUNK) s += psum[(size_t)row*NCHUNK + tid]       * __expf(m0 - mx);
    if (tid + 256 < NCHUNK) s += psum[(size_t)row*NCHUNK + tid + 256] * __expf(m1 - mx);
    #pragma unroll
    for (int off = 1; off < 64; off <<= 1)
        s += __shfl_xor(s, off);
    if ((tid & 63) == 0) ssum[wave] = s;
    __syncthreads();
    if (tid == 0) {
        float st = ssum[0] + ssum[1] + ssum[2] + ssum[3];
        float lse = mx + logf(st);
        int tg = targets[row];
        rowloss[row] = (tg != 0) ? (lse - tlogit[row]) : 0.0f;
    }
}

// ---------------- final sum over rows ----------------
__global__ __launch_bounds__(256) void finalize_kernel(
    const float* __restrict__ rowloss, const int* __restrict__ targets,
    float* __restrict__ out)
{
    const int tid = threadIdx.x;
    float s = 0.f; float c = 0.f;
    for (int i = tid; i < NROWS; i += 256) {
        s += rowloss[i];
        c += (targets[i] != 0) ? 1.0f : 0.0f;
    }
    #pragma unroll
    for (int off = 1; off < 64; off <<= 1) {
        s += __shfl_xor(s, off);
        c += __shfl_xor(c, off);
    }
    __shared__ float ss[4], sc[4];
    const int wave = tid >> 6;
    if ((tid & 63) == 0) { ss[wave] = s; sc[wave] = c; }
    __syncthreads();
    if (tid == 0) {
        float st = ss[0]+ss[1]+ss[2]+ss[3];
        float ct = sc[0]+sc[1]+sc[2]+sc[3];
        out[0] = st / fmaxf(ct, 1.0f);
    }
}

extern "C" void kernel_launch(void* const* d_in, const int* in_sizes, int n_in,
                              void* d_out, int out_size, void* d_ws, size_t ws_size,
                              hipStream_t stream) {
    const float* h       = (const float*)d_in[0];   // (16,512,768) f32
    const int*   wid     = (const int*)  d_in[1];   // (16,512) i32
    const int*   targets = (const int*)  d_in[2];   // (16,256) i32
    const float* Wc      = (const float*)d_in[3];   // (768,32000) f32
    const float* bc      = (const float*)d_in[4];   // (32000,) f32
    float* out = (float*)d_out;

    unsigned char* pooled = (unsigned char*)d_ws;                // 4096*768 fp8
    unsigned char* Wt     = pooled + (size_t)NROWS*HH;           // 32000*768 fp8
    float* pmax  = (float*)(Wt + (size_t)HH*VV);                 // 4096*500
    float* psum  = pmax + (size_t)NROWS*NCHUNK;                  // 4096*500
    float* tlog  = psum + (size_t)NROWS*NCHUNK;                  // 4096
    float* rowl  = tlog + NROWS;                                 // 4096

    pool_kernel<<<NROWS, 256, 0, stream>>>(h, wid, (unsigned int*)pooled);
    wt_kernel<<<dim3(VV/64, HH/64), 256, 0, stream>>>(Wc, Wt);
    logits_kernel<<<NWG, 256, 0, stream>>>(
        pooled, Wt, bc, targets, pmax, psum, tlog);
    reduce_kernel<<<NROWS, 256, 0, stream>>>(pmax, psum, tlog, targets, rowl);
    finalize_kernel<<<1, 256, 0, stream>>>(rowl, targets, out);
}

// Round 15
// 224.794 us; speedup vs baseline: 5.5380x; 1.1337x over previous
//
#include <hip/hip_runtime.h>
#include <math.h>

#define BB 16
#define SS 512
#define HH 768
#define WW 256
#define VV 32000
#define NROWS (BB*WW)          // 4096
#define NCHUNK 500             // 64-wide v chunks
#define BM 128
#define BN 128
#define BK 64                  // fp8: 64 bytes per row per k-tile
#define NKT (HH/BK)            // 12
#define NMT (NROWS/BM)         // 32
#define NVT (VV/BN)            // 250
#define NWG (NMT*NVT)          // 8000
#define WSCALE 64.0f
#define WISCALE (1.0f/64.0f)

typedef __attribute__((ext_vector_type(4))) float f32x4;

#define GLOAD16(g, l) __builtin_amdgcn_global_load_lds( \
    (const __attribute__((address_space(1))) void*)(g), \
    (__attribute__((address_space(3))) void*)(l), 16, 0, 0)

// pack 4 floats -> 4 fp8 e4m3 bytes (OCP)
__device__ __forceinline__ unsigned int pk4_fp8(float a0, float a1, float a2, float a3) {
    int r = __builtin_amdgcn_cvt_pk_fp8_f32(a0, a1, 0, false);
    r = __builtin_amdgcn_cvt_pk_fp8_f32(a2, a3, r, true);
    return (unsigned int)r;
}

// ---------------- pooling: one block per (b, w), fp8 output ----------------
// Stored layout: within each 16B slot, the two 8B halves are swapped when
// row bit3 is set (feeds the conflict-free LDS read swizzle).
__global__ __launch_bounds__(256) void pool_kernel(
    const float* __restrict__ h, const int* __restrict__ wid,
    unsigned int* __restrict__ pooled32)   // 4096 x 192 u32 (=768 fp8)
{
    int blk = blockIdx.x;
    int b = blk >> 8;
    int w = blk & 255;
    int tid = threadIdx.x;
    __shared__ int s_wid[SS];
    for (int i = tid; i < SS; i += 256) s_wid[i] = wid[b*SS + i];
    __syncthreads();
    int lo = 0, hi = SS;
    while (lo < hi) { int mid = (lo + hi) >> 1; if (s_wid[mid] < w) lo = mid + 1; else hi = mid; }
    int start = lo;
    hi = SS;
    while (lo < hi) { int mid = (lo + hi) >> 1; if (s_wid[mid] <= w) lo = mid + 1; else hi = mid; }
    int end = lo;
    int cnt = end - start;

    if (tid < 192) {
        float4 a = {0.f, 0.f, 0.f, 0.f};
        const float* hb = h + (size_t)b*SS*HH;
        for (int s = start; s < end; ++s) {
            float4 r = *(const float4*)&hb[(size_t)s*HH + tid*4];
            a.x += r.x; a.y += r.y; a.z += r.z; a.w += r.w;
        }
        float inv = (cnt > 0) ? (1.0f / (float)cnt) : 0.0f;
        int p = (blk >> 3) & 1;                 // row bit3 -> swap 8B halves
        pooled32[blk*192 + (tid ^ (p << 1))] = pk4_fp8(a.x*inv, a.y*inv, a.z*inv, a.w*inv);
    }
}

// ------- convert + transpose W: (768,32000) f32 -> (32000,768) fp8 (x64 scale) -------
// Same half-swap-by-row-bit3 storage as pooled.
__global__ __launch_bounds__(256) void wt_kernel(
    const float* __restrict__ Wc, unsigned char* __restrict__ Wt)
{
    const int v0 = blockIdx.x * 64;
    const int k0 = blockIdx.y * 64;
    const int t = threadIdx.x;
    __shared__ float S[64][65];
    #pragma unroll
    for (int j = 0; j < 4; ++j) {
        int idx = t + j*256;
        int kr = idx >> 4;
        int vs = idx & 15;
        float4 f = *(const float4*)&Wc[(size_t)(k0+kr)*VV + v0 + vs*4];
        S[kr][vs*4+0] = f.x; S[kr][vs*4+1] = f.y;
        S[kr][vs*4+2] = f.z; S[kr][vs*4+3] = f.w;
    }
    __syncthreads();
    #pragma unroll
    for (int j = 0; j < 2; ++j) {
        int idx = t + j*256;
        int vi = idx >> 3;     // 0..63 (row within tile)
        int ks = idx & 7;      // 0..7 (8B seg)
        float f[8];
        #pragma unroll
        for (int i = 0; i < 8; ++i) f[i] = S[ks*8+i][vi] * WSCALE;
        uint2 o;
        o.x = pk4_fp8(f[0], f[1], f[2], f[3]);
        o.y = pk4_fp8(f[4], f[5], f[6], f[7]);
        int p = (vi >> 3) & 1;                  // row bit3 -> swap 8B halves
        *(uint2*)&Wt[(size_t)(v0+vi)*HH + k0 + (ks ^ p)*8] = o;
    }
}

// ---------------- fp8 MFMA GEMM, 128x128 tile, BK=64, 4 blocks/CU (R9) + T5 ----------------
// 256 threads = 4 waves (2M x 2N), wave tile 64x64, acc[4][4]=64 VGPR.
// LDS: 2 dbuf x (A 8KB + B 8KB) = 32 KB; launch_bounds(256,4) caps VGPR 128
// -> 4 blocks/CU = 16 waves in 4 INDEPENDENT barrier groups (the best measured
// structure: R9 = 217us; R14's depth-2 counted-vmcnt at 3 blocks = 250us).
// m97-style loop: STAGE(kt+1) at top, compiler waits, one barrier per k-step.
// + T5: setprio(1) around the MFMA cluster -- independent-block regime is the
// one where setprio measured positive (m191); lockstep regime was null (m190).
// Swizzle (conflict-free, measured 0): LDS 16B slot s of row r holds global
// slot s^((r>>1)&3); global storage pre-swaps 8B halves by row bit3; read
// offset covers all 4 r16 bits.
__global__ __launch_bounds__(256, 4) void logits_kernel(
    const unsigned char* __restrict__ Pb, const unsigned char* __restrict__ Wt,
    const float* __restrict__ bc, const int* __restrict__ targets,
    float* __restrict__ pmax, float* __restrict__ psum,
    float* __restrict__ tlogit)
{
    __shared__ unsigned char Alds[2][BM*BK];   // 2 x 8 KB
    __shared__ unsigned char Blds[2][BN*BK];   // 2 x 8 KB

    // XCD swizzle (NWG = 8000, divisible by 8), m-minor within XCD chunk
    const int id = blockIdx.x;
    const int wg = (id & 7) * (NWG/8) + (id >> 3);
    const int mt = wg % NMT;
    const int vt = wg / NMT;

    const int t = threadIdx.x;
    const int w = t >> 6;           // wave 0..3
    const int lane = t & 63;
    const int r16 = lane & 15;
    const int kb = lane >> 4;       // 0..3 (8-byte k-seg within 32)
    const int wr = w >> 1;          // 0..1 (M)
    const int wc = w & 1;           // 0..1 (N)
    const int row0 = mt * BM;
    const int v0 = vt * BN;

    // staging: one call = 64 lanes x 16 B = 16 rows x 64 B; lane = rr*4 + s
    const int rr = lane >> 2;                     // 0..15 row within call
    const int sg = (lane & 3) ^ ((rr >> 1) & 3);  // pre-swizzled global 16B slot

    // A: 8 calls (2/wave), B: 8 calls (2/wave) -> 4 loads/thread per STAGE
    #define STAGE(BUF, KT) do {                                                   \
        const int k0_ = (KT) * BK;                                                \
        _Pragma("unroll")                                                         \
        for (int j_ = 0; j_ < 2; ++j_) {                                          \
            int ca_ = w*2 + j_;                                                   \
            GLOAD16(Pb + (size_t)(row0 + ca_*16 + rr)*HH + k0_ + sg*16,           \
                    &Alds[BUF][ca_*1024]);                                        \
            GLOAD16(Wt + (size_t)(v0 + ca_*16 + rr)*HH + k0_ + sg*16,             \
                    &Blds[BUF][ca_*1024]);                                        \
        }                                                                         \
    } while (0)

    f32x4 acc[4][4];
    #pragma unroll
    for (int mf = 0; mf < 4; ++mf)
        #pragma unroll
        for (int nf = 0; nf < 4; ++nf)
            acc[mf][nf] = (f32x4){0.f, 0.f, 0.f, 0.f};

    STAGE(0, 0);
    __syncthreads();

    const int swz2 = (r16 >> 1) & 3;
    const int swz3 = (r16 >> 3) & 1;

    for (int kt = 0; kt < NKT; ++kt) {
        const int buf = kt & 1;
        if (kt + 1 < NKT) STAGE(buf ^ 1, kt + 1);

        long af[4][2], bfv[4][2];
        #pragma unroll
        for (int ks = 0; ks < 2; ++ks) {
            const int idx8 = ks*4 + kb;                       // 0..7
            const int off = (((idx8 >> 1) ^ swz2) << 4) | (((idx8 & 1) ^ swz3) << 3);
            #pragma unroll
            for (int mf = 0; mf < 4; ++mf)
                af[mf][ks] = *(const long*)&Alds[buf][(wr*64 + mf*16 + r16)*BK + off];
            #pragma unroll
            for (int nf = 0; nf < 4; ++nf)
                bfv[nf][ks] = *(const long*)&Blds[buf][(wc*64 + nf*16 + r16)*BK + off];
        }

        __builtin_amdgcn_s_setprio(1);
        #pragma unroll
        for (int ks = 0; ks < 2; ++ks)
            #pragma unroll
            for (int mf = 0; mf < 4; ++mf)
                #pragma unroll
                for (int nf = 0; nf < 4; ++nf)
                    acc[mf][nf] = __builtin_amdgcn_mfma_f32_16x16x32_fp8_fp8(
                        af[mf][ks], bfv[nf][ks], acc[mf][nf], 0, 0, 0);
        __builtin_amdgcn_s_setprio(0);

        __syncthreads();
    }

    // epilogue: unscale + bias + per-row max/sumexp over this wave's 64 cols
    const int cchunk = vt*2 + wc;
    float bias[4];
    #pragma unroll
    for (int nf = 0; nf < 4; ++nf) bias[nf] = bc[v0 + wc*64 + nf*16 + r16];

    #pragma unroll
    for (int mf = 0; mf < 4; ++mf) {
        #pragma unroll
        for (int j = 0; j < 4; ++j) {
            const int row = row0 + wr*64 + mf*16 + kb*4 + j;
            float v[4]; float mx = -INFINITY;
            #pragma unroll
            for (int nf = 0; nf < 4; ++nf) {
                v[nf] = acc[mf][nf][j]*WISCALE + bias[nf];
                mx = fmaxf(mx, v[nf]);
            }
            #pragma unroll
            for (int off = 1; off < 16; off <<= 1)
                mx = fmaxf(mx, __shfl_xor(mx, off, 16));
            float se = 0.f;
            #pragma unroll
            for (int nf = 0; nf < 4; ++nf) se += __expf(v[nf] - mx);
            #pragma unroll
            for (int off = 1; off < 16; off <<= 1)
                se += __shfl_xor(se, off, 16);
            if (r16 == 0) {
                pmax[(size_t)row*NCHUNK + cchunk] = mx;
                psum[(size_t)row*NCHUNK + cchunk] = se;
            }
            int tg = targets[row];
            int base = v0 + wc*64 + r16;
            #pragma unroll
            for (int nf = 0; nf < 4; ++nf)
                if (tg == base + nf*16) tlogit[row] = v[nf];
        }
    }
}

// ---------------- combine chunk partials -> per-row loss ----------------
__global__ __launch_bounds__(256) void reduce_kernel(
    const float* __restrict__ pmax, const float* __restrict__ psum,
    const float* __restrict__ tlogit, const int* __restrict__ targets,
    float* __restrict__ rowloss)
{
    const int row = blockIdx.x;
    const int tid = threadIdx.x;
    float m0 = (tid       < NCHUNK) ? pmax[(size_t)row*NCHUNK + tid]       : -INFINITY;
    float m1 = (tid + 256 < NCHUNK) ? pmax[(size_t)row*NCHUNK + tid + 256] : -INFINITY;
    float mw = fmaxf(m0, m1);
    #pragma unroll
    for (int off = 1; off < 64; off <<= 1)
        mw = fmaxf(mw, __shfl_xor(mw, off));
    __shared__ float smax[4];
    __shared__ float ssum[4];
    const int wave = tid >> 6;
    if ((tid & 63) == 0) smax[wave] = mw;
    __syncthreads();
    float mx = fmaxf(fmaxf(smax[0], smax[1]), fmaxf(smax[2], smax[3]));
    float s = 0.f;
    if (tid       < NCHUNK) s += psum[(size_t)row*NCHUNK + tid]       * __expf(m0 - mx);
    if (tid + 256 < NCHUNK) s += psum[(size_t)row*NCHUNK + tid + 256] * __expf(m1 - mx);
    #pragma unroll
    for (int off = 1; off < 64; off <<= 1)
        s += __shfl_xor(s, off);
    if ((tid & 63) == 0) ssum[wave] = s;
    __syncthreads();
    if (tid == 0) {
        float st = ssum[0] + ssum[1] + ssum[2] + ssum[3];
        float lse = mx + logf(st);
        int tg = targets[row];
        rowloss[row] = (tg != 0) ? (lse - tlogit[row]) : 0.0f;
    }
}

// ---------------- final sum over rows ----------------
__global__ __launch_bounds__(256) void finalize_kernel(
    const float* __restrict__ rowloss, const int* __restrict__ targets,
    float* __restrict__ out)
{
    const int tid = threadIdx.x;
    float s = 0.f; float c = 0.f;
    for (int i = tid; i < NROWS; i += 256) {
        s += rowloss[i];
        c += (targets[i] != 0) ? 1.0f : 0.0f;
    }
    #pragma unroll
    for (int off = 1; off < 64; off <<= 1) {
        s += __shfl_xor(s, off);
        c += __shfl_xor(c, off);
    }
    __shared__ float ss[4], sc[4];
    const int wave = tid >> 6;
    if ((tid & 63) == 0) { ss[wave] = s; sc[wave] = c; }
    __syncthreads();
    if (tid == 0) {
        float st = ss[0]+ss[1]+ss[2]+ss[3];
        float ct = sc[0]+sc[1]+sc[2]+sc[3];
        out[0] = st / fmaxf(ct, 1.0f);
    }
}

extern "C" void kernel_launch(void* const* d_in, const int* in_sizes, int n_in,
                              void* d_out, int out_size, void* d_ws, size_t ws_size,
                              hipStream_t stream) {
    const float* h       = (const float*)d_in[0];   // (16,512,768) f32
    const int*   wid     = (const int*)  d_in[1];   // (16,512) i32
    const int*   targets = (const int*)  d_in[2];   // (16,256) i32
    const float* Wc      = (const float*)d_in[3];   // (768,32000) f32
    const float* bc      = (const float*)d_in[4];   // (32000,) f32
    float* out = (float*)d_out;

    unsigned char* pooled = (unsigned char*)d_ws;                // 4096*768 fp8
    unsigned char* Wt     = pooled + (size_t)NROWS*HH;           // 32000*768 fp8
    float* pmax  = (float*)(Wt + (size_t)HH*VV);                 // 4096*500
    float* psum  = pmax + (size_t)NROWS*NCHUNK;                  // 4096*500
    float* tlog  = psum + (size_t)NROWS*NCHUNK;                  // 4096
    float* rowl  = tlog + NROWS;                                 // 4096

    pool_kernel<<<NROWS, 256, 0, stream>>>(h, wid, (unsigned int*)pooled);
    wt_kernel<<<dim3(VV/64, HH/64), 256, 0, stream>>>(Wc, Wt);
    logits_kernel<<<NWG, 256, 0, stream>>>(
        pooled, Wt, bc, targets, pmax, psum, tlog);
    reduce_kernel<<<NROWS, 256, 0, stream>>>(pmax, psum, tlog, targets, rowl);
    finalize_kernel<<<1, 256, 0, stream>>>(rowl, targets, out);
}